// Round 10
// baseline (158.131 us; speedup 1.0000x reference)
//
#include <hip/hip_runtime.h>

typedef float f32x4 __attribute__((ext_vector_type(4)));
typedef float f32x16 __attribute__((ext_vector_type(16)));
typedef short bf16x8 __attribute__((ext_vector_type(8)));
typedef unsigned short u16;
typedef unsigned int u32;
typedef unsigned int u32x2 __attribute__((ext_vector_type(2)));

#define MFMA(a, b, c) __builtin_amdgcn_mfma_f32_16x16x32_bf16((a), (b), (c), 0, 0, 0)
#define MFMA32(a, b, c) __builtin_amdgcn_mfma_f32_32x32x16_bf16((a), (b), (c), 0, 0, 0)

static __device__ __forceinline__ u16 f2bf(float f) {
    union { float f; u32 u; } v; v.f = f;
    u32 r = v.u + 0x7FFFu + ((v.u >> 16) & 1u);
    return (u16)(r >> 16);
}

// pack two fp32 -> two bf16 in one u32 (a low, b high)
static __device__ __forceinline__ u32 pkbf(float a, float b) {
    u32 ua = __float_as_uint(a) + 0x8000u;
    u32 ub = __float_as_uint(b) + 0x8000u;
    return __builtin_amdgcn_perm(ub, ua, 0x07060302);
}

// async global->LDS DMA, 16B per lane: LDS dest = wave-uniform base + lane*16.
static __device__ __forceinline__ void gll16(const u16* g, u16* l) {
    __builtin_amdgcn_global_load_lds(
        (const __attribute__((address_space(1))) u32*)(const void*)g,
        (__attribute__((address_space(3))) u32*)(void*)l, 16, 0, 0);
}

// barrier with vmcnt drain (DMA fills tracked by vmcnt).
#define BAR_VM() do { \
    asm volatile("s_waitcnt vmcnt(0)" ::: "memory"); \
    __builtin_amdgcn_s_barrier(); \
    asm volatile("" ::: "memory"); \
} while (0)

// barrier draining only LDS ops (ds_writes visible; loads may stay in flight
// when their data was already consumed / ds_write-forwarded).
#define BAR_LGKM() do { \
    asm volatile("s_waitcnt lgkmcnt(0)" ::: "memory"); \
    __builtin_amdgcn_s_barrier(); \
} while (0)

// ---------------------------------------------------------------------------
// Kernel 1: prep = wcvt (blocks 0..255) + gn_stats (blocks 256..511).
// ---------------------------------------------------------------------------
__global__ __launch_bounds__(256) void prep_kernel(
    const float* __restrict__ wq, const float* __restrict__ wk,
    const float* __restrict__ wv, const float* __restrict__ wo,
    const float* __restrict__ x, u16* __restrict__ Wbf,
    float2* __restrict__ part) {
    int blk = blockIdx.x;
    int t = threadIdx.x;
    if (blk < 256) {
        int base = (blk * 256 + t) * 4;
        int p = base >> 16;
        int off = base & 65535;
        const float* W = (p == 0) ? wq : ((p == 1) ? wk : ((p == 2) ? wv : wo));
        float sc = (p == 0) ? 0.09014009048f : 1.0f;   // log2(e)/16
        float4 v = *(const float4*)(W + off);
        uint2 pk;
        pk.x = pkbf(v.x * sc, v.y * sc);
        pk.y = pkbf(v.z * sc, v.w * sc);
        *(uint2*)(Wbf + base) = pk;
        return;
    }
    int sblk = blk - 256;
    int bg = sblk >> 2, quarter = sblk & 3;
    const float* xp = x + (size_t)bg * 32768 + quarter * 8192;

    float s = 0.f, ss = 0.f;
#pragma unroll
    for (int rep = 0; rep < 8; ++rep) {
        float4 v = *(const float4*)(xp + t * 4 + rep * 1024);
        s += v.x + v.y + v.z + v.w;
        ss += v.x * v.x + v.y * v.y + v.z * v.z + v.w * v.w;
    }
    for (int off = 1; off < 64; off <<= 1) {
        s += __shfl_xor(s, off);
        ss += __shfl_xor(ss, off);
    }
    __shared__ float red[8];
    int lane = t & 63, w = t >> 6;
    if (lane == 0) { red[w] = s; red[4 + w] = ss; }
    __syncthreads();
    if (t == 0) {
        part[sblk] = make_float2(red[0] + red[1] + red[2] + red[3],
                                 red[4] + red[5] + red[6] + red[7]);
    }
}

// ---------------------------------------------------------------------------
// Kernel 2: QKV GEMM, fused GroupNorm B-stage (R21 coalesced layout).
// ---------------------------------------------------------------------------
__global__ __launch_bounds__(256) void qkv_gemm(
    const float* __restrict__ x, const float* __restrict__ gw,
    const float* __restrict__ gb, const float2* __restrict__ part,
    const u16* __restrict__ Wbf,
    u16* __restrict__ Q, u16* __restrict__ K, u16* __restrict__ V) {
    int b = blockIdx.y & 1;
    int p = blockIdx.y >> 1;
    const u16* W = Wbf + p * 65536;
    int m0 = (blockIdx.x & 1) * 128;
    int n0 = (blockIdx.x >> 1) * 64;

    __shared__ u16 a_s[128 * 40];
    __shared__ u16 b_s[64 * 40];
    __shared__ float wgt_s[256], bia_s[256];

    int t = threadIdx.x;
    int lane = t & 63, wave = t >> 6;
    int wm = wave & 1, wn = wave >> 1;
    int r = lane & 15, qd = lane >> 4;

    {
        int c = t;
        int g = c >> 3;
        float s = 0.f, ss = 0.f;
#pragma unroll
        for (int q = 0; q < 4; ++q) {
            float2 pp = part[(b * 32 + g) * 4 + q];
            s += pp.x; ss += pp.y;
        }
        float mu = s * (1.f / 32768.f);
        float var = ss * (1.f / 32768.f) - mu * mu;
        float rstd = rsqrtf(var + 1e-5f);
        float wg = gw[c] * rstd;
        wgt_s[c] = wg;
        bia_s[c] = gb[c] - mu * wg;
    }
    __syncthreads();

    f32x4 acc[4][2];
#pragma unroll
    for (int i = 0; i < 4; ++i)
#pragma unroll
        for (int j = 0; j < 2; ++j) acc[i][j] = (f32x4){0.f, 0.f, 0.f, 0.f};

    int srow = t >> 1;
    int scp = (t & 1) * 16;
    int bn = t & 63;                     // n within tile (lane -> coalesced)
    int bw = t >> 6;                     // wave = logical c-granule
    int bswz = ((bn >> 3) & 3) ^ (((bn >> 5) & 1) << 1);
    int bgp = ((bw ^ bswz) << 3);

    for (int kk = 0; kk < 256; kk += 32) {
        __syncthreads();
        {
            const u16* src = W + (m0 + srow) * 256 + kk + scp;
            *(uint4*)(a_s + srow * 40 + scp) = *(const uint4*)(src);
            *(uint4*)(a_s + srow * 40 + scp + 8) = *(const uint4*)(src + 8);
        }
        {
            const float* xcol = x + (size_t)(b * 256 + kk + bw * 8) * 4096 + n0 + bn;
            float xv[8];
#pragma unroll
            for (int j = 0; j < 8; ++j) xv[j] = xcol[(size_t)j * 4096];
#pragma unroll
            for (int j = 0; j < 8; ++j) {
                int c = kk + bw * 8 + j;
                b_s[bn * 40 + bgp + j] = f2bf(xv[j] * wgt_s[c] + bia_s[c]);
            }
        }
        __syncthreads();

        bf16x8 af[4], bf[2];
#pragma unroll
        for (int mt = 0; mt < 4; ++mt)
            af[mt] = *(const bf16x8*)(a_s + (wm * 64 + mt * 16 + r) * 40 + qd * 8);
#pragma unroll
        for (int nt = 0; nt < 2; ++nt) {
            int row = wn * 32 + nt * 16 + r;
            int rswz = ((row >> 3) & 3) ^ (((row >> 5) & 1) << 1);
            bf[nt] = *(const bf16x8*)(b_s + row * 40 + ((qd ^ rswz) << 3));
        }
        if (p == 2) {
#pragma unroll
            for (int mt = 0; mt < 4; ++mt)
#pragma unroll
                for (int nt = 0; nt < 2; ++nt)
                    acc[mt][nt] = MFMA(bf[nt], af[mt], acc[mt][nt]);
        } else {
#pragma unroll
            for (int mt = 0; mt < 4; ++mt)
#pragma unroll
                for (int nt = 0; nt < 2; ++nt)
                    acc[mt][nt] = MFMA(af[mt], bf[nt], acc[mt][nt]);
        }
    }

    if (p < 2) {
        u16* dst = (p == 0) ? Q : K;
#pragma unroll
        for (int mt = 0; mt < 4; ++mt) {
#pragma unroll
            for (int nt = 0; nt < 2; ++nt) {
                int o0 = m0 + wm * 64 + mt * 16 + qd * 4;
                int s = n0 + wn * 32 + nt * 16 + r;
                int h = o0 >> 6, d0 = o0 & 63;
                uint2 pk;
                pk.x = pkbf(acc[mt][nt][0], acc[mt][nt][1]);
                pk.y = pkbf(acc[mt][nt][2], acc[mt][nt][3]);
                *(uint2*)(dst + ((size_t)((b * 4 + h) * 4096 + s)) * 64 + d0) = pk;
            }
        }
    } else {
#pragma unroll
        for (int mt = 0; mt < 4; ++mt) {
#pragma unroll
            for (int nt = 0; nt < 2; ++nt) {
                int o = m0 + wm * 64 + mt * 16 + r;
                int h = o >> 6, d = o & 63;
                int sb = n0 + wn * 32 + nt * 16 + qd * 4;
                uint2 pk;
                pk.x = pkbf(acc[mt][nt][0], acc[mt][nt][1]);
                pk.y = pkbf(acc[mt][nt][2], acc[mt][nt][3]);
                *(uint2*)(V + ((size_t)((b * 4 + h) * 64 + d)) * 4096 + sb) = pk;
            }
        }
    }
}

// ---------------------------------------------------------------------------
// Kernel 3: flash attention (R20/R21 structure: QT=1 + DMA staging, 64 VGPR
// + 32 AGPR, 4 blocks/CU, nsplit=4). UNCHANGED this round.
// ---------------------------------------------------------------------------
template <int QT>
__global__ __launch_bounds__(256, QT == 1 ? 4 : 2) void attn_kernel(
    const u16* __restrict__ Q, const u16* __restrict__ K,
    const u16* __restrict__ V, u16* __restrict__ Opart,
    float* __restrict__ Lpart, int nk32) {
    int bh = blockIdx.x & 7, sp = blockIdx.x >> 3;
    int qb = blockIdx.y;
    int t = threadIdx.x, lane = t & 63, w = t >> 6;
    int qn = lane & 31, h = lane >> 5;

    const size_t bhoff = (size_t)bh * 4096 * 64;
    int q0 = (qb * 4 + w) * (32 * QT);
    int kbase = sp * nk32 * 32;

    __shared__ u16 smem[16384];

    bf16x8 qf[QT][4];
#pragma unroll
    for (int qt = 0; qt < QT; ++qt)
#pragma unroll
        for (int c = 0; c < 4; ++c)
            qf[qt][c] = *(const bf16x8*)(Q + bhoff +
                (size_t)(q0 + qt * 32 + qn) * 64 + c * 16 + h * 8);

    f32x16 oacc[2][QT];
#pragma unroll
    for (int dt = 0; dt < 2; ++dt)
#pragma unroll
        for (int qt = 0; qt < QT; ++qt)
#pragma unroll
            for (int i = 0; i < 16; ++i) oacc[dt][qt][i] = 0.f;
    float lacc[QT];
#pragma unroll
    for (int qt = 0; qt < QT; ++qt) lacc[qt] = 0.f;

    const u16* Kp = K + bhoff;
    const u16* Vp = V + bhoff;

    int gs = (lane & 7) ^ (lane >> 3);
    int rbase = (w & 1) * 32 + (lane >> 3);

    auto fill = [&](int bufsel, int kp) {
        u16* ld = smem + bufsel * 8192 + w * 2048;
        if (w < 2) {
            const u16* s = Kp + (size_t)(kp + rbase) * 64 + gs * 8;
#pragma unroll
            for (int j = 0; j < 4; ++j) gll16(s + j * 512, ld + j * 512);
        } else {
            const u16* s = Vp + (size_t)rbase * 4096 + kp + gs * 8;
#pragma unroll
            for (int j = 0; j < 4; ++j) gll16(s + j * 32768, ld + j * 512);
        }
    };

    int sw = qn & 7;
    auto step = [&](const u16* buf, int j) {
        bf16x8 kf[4], vf[2][2];
        int kr = j * 32 + qn;
#pragma unroll
        for (int c = 0; c < 4; ++c)
            kf[c] = *(const bf16x8*)(buf + kr * 64 + (((c * 2 + h) ^ sw) << 3));
#pragma unroll
        for (int dt = 0; dt < 2; ++dt) {
            int d = dt * 32 + qn;
#pragma unroll
            for (int kc = 0; kc < 2; ++kc) {
                int g = j * 4 + kc * 2 + h;
                vf[dt][kc] = *(const bf16x8*)(buf + 4096 + d * 64 + ((g ^ sw) << 3));
            }
        }
#pragma unroll
        for (int qt = 0; qt < QT; ++qt) {
            f32x16 s;
#pragma unroll
            for (int i = 0; i < 16; ++i) s[i] = 0.f;
            __builtin_amdgcn_s_setprio(1);
#pragma unroll
            for (int c = 0; c < 4; ++c) s = MFMA32(kf[c], qf[qt][c], s);
            __builtin_amdgcn_s_setprio(0);

            float e[16];
#pragma unroll
            for (int i = 0; i < 16; ++i)
                e[i] = __builtin_amdgcn_exp2f(s[i]);
            float t0 = (e[0] + e[1]) + (e[2] + e[3]);
            float t1 = (e[4] + e[5]) + (e[6] + e[7]);
            float t2 = (e[8] + e[9]) + (e[10] + e[11]);
            float t3 = (e[12] + e[13]) + (e[14] + e[15]);
            lacc[qt] += (t0 + t1) + (t2 + t3);

            u32 p[8];
#pragma unroll
            for (int i = 0; i < 8; ++i) p[i] = pkbf(e[2 * i], e[2 * i + 1]);

            u32x2 r0 = __builtin_amdgcn_permlane32_swap(p[0], p[2], false, false);
            u32x2 r1 = __builtin_amdgcn_permlane32_swap(p[1], p[3], false, false);
            u32x2 r2 = __builtin_amdgcn_permlane32_swap(p[4], p[6], false, false);
            u32x2 r3 = __builtin_amdgcn_permlane32_swap(p[5], p[7], false, false);
            uint4 pau = {r0[0], r1[0], r0[1], r1[1]};
            uint4 pbu = {r2[0], r3[0], r2[1], r3[1]};
            bf16x8 pA = *(const bf16x8*)&pau;
            bf16x8 pB = *(const bf16x8*)&pbu;

            __builtin_amdgcn_s_setprio(1);
#pragma unroll
            for (int dt = 0; dt < 2; ++dt) {
                oacc[dt][qt] = MFMA32(vf[dt][0], pA, oacc[dt][qt]);
                oacc[dt][qt] = MFMA32(vf[dt][1], pB, oacc[dt][qt]);
            }
            __builtin_amdgcn_s_setprio(0);
        }
    };

    int npair = nk32 >> 1;
    fill(0, kbase);
    if (npair > 1) fill(1, kbase + 64);
    BAR_VM();

    for (int i = 0; i < npair; ++i) {
        const u16* cur = smem + (i & 1) * 8192;
        step(cur, 0);
        step(cur, 1);
        BAR_VM();
        if (i + 2 < npair) fill(i & 1, kbase + (i + 2) * 64);
    }

    float lfull[QT];
#pragma unroll
    for (int qt = 0; qt < QT; ++qt)
        lfull[qt] = lacc[qt] + __shfl_xor(lacc[qt], 32);

    u16* my = smem + w * (32 * 72);
    size_t obase = ((size_t)sp * 8 + bh) * 4096 + q0;
#pragma unroll
    for (int qt = 0; qt < QT; ++qt) {
#pragma unroll
        for (int dt = 0; dt < 2; ++dt) {
#pragma unroll
            for (int g = 0; g < 4; ++g) {
                int d0 = g * 8 + h * 4 + dt * 32;
                uint2 pk;
                pk.x = pkbf(oacc[dt][qt][4 * g], oacc[dt][qt][4 * g + 1]);
                pk.y = pkbf(oacc[dt][qt][4 * g + 2], oacc[dt][qt][4 * g + 3]);
                *(uint2*)(my + qn * 72 + d0) = pk;
            }
        }
#pragma unroll
        for (int rr = 0; rr < 4; ++rr) {
            int row = rr * 8 + (lane >> 3), ch = lane & 7;
            uint4 v = *(const uint4*)(my + row * 72 + ch * 8);
            *(uint4*)(Opart + (obase + qt * 32 + row) * 64 + ch * 8) = v;
        }
    }
    if (h == 0) {
#pragma unroll
        for (int qt = 0; qt < QT; ++qt)
            Lpart[obase + qt * 32 + qn] = lfull[qt];
    }
}

// ---------------------------------------------------------------------------
// Kernel 4 (FUSED combine + output GEMM). R22: reads Opart/Lpart directly
// (attnT + separate combine kernel eliminated: -1 launch, -8MB traffic).
// Per k-step the B operand is ONE head-slice of channels [kk,kk+32): the
// combine (sum nsplit partials, scale by 1/l) happens inline into b_s.
// linv[hh][row] precomputed once per block. Tiles 64Mx32N, grid (512,2)
// = 1024 blocks = 4 blocks/CU (the proven occupancy config). BAR_LGKM.
// ---------------------------------------------------------------------------
__global__ __launch_bounds__(256) void out_gemm(
    const u16* __restrict__ Opart, const float* __restrict__ Lpart,
    const u16* __restrict__ W3, const float* __restrict__ bo,
    const float* __restrict__ x, float* __restrict__ out, int nsplit) {
    int b = blockIdx.y;
    int m0 = (blockIdx.x & 3) * 64;
    int n0 = (blockIdx.x >> 2) * 32;

    __shared__ u16 a_s[64 * 40];
    __shared__ u16 b_s[32 * 40];
    __shared__ float linv_s[4][32];

    int t = threadIdx.x;
    int lane = t & 63, wave = t >> 6;
    int wm = wave & 1, wn = wave >> 1;
    int r = lane & 15, qd = lane >> 4;

    if (t < 128) {
        int hh = t >> 5, row = t & 31;
        size_t gi = (size_t)(b * 4 + hh) * 4096 + n0 + row;
        float l = 0.f;
        for (int s = 0; s < nsplit; ++s) l += Lpart[(size_t)s * 32768 + gi];
        linv_s[hh][row] = 1.f / l;
    }

    f32x4 acc[2];
    acc[0] = (f32x4){0.f, 0.f, 0.f, 0.f};
    acc[1] = (f32x4){0.f, 0.f, 0.f, 0.f};

    int arow = t >> 2, acp = (t & 3) * 8;    // A: 64 rows x 32 cols, 16B/thread
    int brow = t >> 3, bcp = (t & 7) * 4;    // B: 32 rows x 32 cols, 4 vals/thread
    __syncthreads();                          // linv_s ready

    for (int kk = 0; kk < 256; kk += 32) {
        {
            const u16* src = W3 + (m0 + arow) * 256 + kk + acp;
            *(uint4*)(a_s + arow * 40 + acp) = *(const uint4*)(src);
        }
        {
            int hh = kk >> 6, dk = kk & 63;
            size_t base = ((size_t)(b * 4 + hh) * 4096 + n0 + brow) * 64 + dk + bcp;
            float a0 = 0.f, a1 = 0.f, a2 = 0.f, a3 = 0.f;
            for (int s = 0; s < nsplit; ++s) {
                uint2 v = *(const uint2*)(Opart + (size_t)s * 2097152 + base);
                a0 += __uint_as_float(v.x << 16);
                a1 += __uint_as_float(v.x & 0xFFFF0000u);
                a2 += __uint_as_float(v.y << 16);
                a3 += __uint_as_float(v.y & 0xFFFF0000u);
            }
            float li = linv_s[hh][brow];
            uint2 pk;
            pk.x = pkbf(a0 * li, a1 * li);
            pk.y = pkbf(a2 * li, a3 * li);
            *(uint2*)(b_s + brow * 40 + bcp) = pk;
        }
        BAR_LGKM();

        bf16x8 af[2], bf;
#pragma unroll
        for (int mt = 0; mt < 2; ++mt)
            af[mt] = *(const bf16x8*)(a_s + (wm * 32 + mt * 16 + r) * 40 + qd * 8);
        bf = *(const bf16x8*)(b_s + (wn * 16 + r) * 40 + qd * 8);
#pragma unroll
        for (int mt = 0; mt < 2; ++mt)
            acc[mt] = MFMA(af[mt], bf, acc[mt]);
        BAR_LGKM();                           // MFMA reads done before restage
    }

#pragma unroll
    for (int mt = 0; mt < 2; ++mt) {
#pragma unroll
        for (int j = 0; j < 4; ++j) {
            int o = m0 + wm * 32 + mt * 16 + qd * 4 + j;
            int s = n0 + wn * 16 + r;
            size_t idx = (size_t)(b * 256 + o) * 4096 + s;
            out[idx] = acc[mt][j] + bo[o] + x[idx];
        }
    }
}

// ---------------------------------------------------------------------------
extern "C" void kernel_launch(void* const* d_in, const int* in_sizes, int n_in,
                              void* d_out, int out_size, void* d_ws, size_t ws_size,
                              hipStream_t stream) {
    const float* x = (const float*)d_in[0];
    const float* gn_w = (const float*)d_in[1];
    const float* gn_b = (const float*)d_in[2];
    const float* wq = (const float*)d_in[3];
    const float* wk = (const float*)d_in[4];
    const float* wv = (const float*)d_in[5];
    const float* wo = (const float*)d_in[6];
    const float* bo = (const float*)d_in[7];
    float* out = (float*)d_out;

    char* ws = (char*)d_ws;
    u16* Q     = (u16*)(ws + (4u << 20));           // [b][h][s][d] (scaled log2e/16)
    u16* Kp    = (u16*)(ws + (8u << 20));           // [b][h][s][d]
    u16* Vp    = (u16*)(ws + (12u << 20));          // [b][h][d][s]
    u16* Wbf   = (u16*)(ws + (16u << 20));          // 512 KB
    float2* part = (float2*)(ws + (16u << 20) + 524288);

    size_t opart_off = (size_t)17 << 20;
    size_t osplit = 8ull * 4096 * 64 * 2;            // 4 MB per split
    int nsplit = (ws_size >= opart_off + 4 * osplit + 4ull * 32768 * 4 + 4096) ? 4 : 2;
    u16* Opart = (u16*)(ws + opart_off);
    float* Lpart = (float*)(ws + opart_off + (size_t)nsplit * osplit);

    prep_kernel<<<512, 256, 0, stream>>>(wq, wk, wv, wo, x, Wbf, part);
    qkv_gemm<<<dim3(128, 6), 256, 0, stream>>>(x, gn_w, gn_b, part, Wbf, Q, Kp, Vp);
    attn_kernel<1><<<dim3(8 * nsplit, 32), 256, 0, stream>>>(
        Q, Kp, Vp, Opart, Lpart, 128 / nsplit);
    out_gemm<<<dim3(512, 2), 256, 0, stream>>>(
        Opart, Lpart, Wbf + 3 * 65536, bo, x, out, nsplit);
}

// Round 11
// 139.829 us; speedup vs baseline: 1.1309x; 1.1309x over previous
//
#include <hip/hip_runtime.h>

typedef float f32x4 __attribute__((ext_vector_type(4)));
typedef float f32x16 __attribute__((ext_vector_type(16)));
typedef short bf16x8 __attribute__((ext_vector_type(8)));
typedef unsigned short u16;
typedef unsigned int u32;
typedef unsigned int u32x2 __attribute__((ext_vector_type(2)));

#define MFMA(a, b, c) __builtin_amdgcn_mfma_f32_16x16x32_bf16((a), (b), (c), 0, 0, 0)
#define MFMA32(a, b, c) __builtin_amdgcn_mfma_f32_32x32x16_bf16((a), (b), (c), 0, 0, 0)

static __device__ __forceinline__ u16 f2bf(float f) {
    union { float f; u32 u; } v; v.f = f;
    u32 r = v.u + 0x7FFFu + ((v.u >> 16) & 1u);
    return (u16)(r >> 16);
}

// pack two fp32 -> two bf16 in one u32 (a low, b high)
static __device__ __forceinline__ u32 pkbf(float a, float b) {
    u32 ua = __float_as_uint(a) + 0x8000u;
    u32 ub = __float_as_uint(b) + 0x8000u;
    return __builtin_amdgcn_perm(ub, ua, 0x07060302);
}

// async global->LDS DMA, 16B per lane: LDS dest = wave-uniform base + lane*16.
static __device__ __forceinline__ void gll16(const u16* g, u16* l) {
    __builtin_amdgcn_global_load_lds(
        (const __attribute__((address_space(1))) u32*)(const void*)g,
        (__attribute__((address_space(3))) u32*)(void*)l, 16, 0, 0);
}

// barrier with vmcnt drain (DMA fills tracked by vmcnt).
#define BAR_VM() do { \
    asm volatile("s_waitcnt vmcnt(0)" ::: "memory"); \
    __builtin_amdgcn_s_barrier(); \
    asm volatile("" ::: "memory"); \
} while (0)

// barrier draining only LDS ops; in-flight global loads may cross (their
// data is consumed at the register-use site via compiler vmcnt waits).
#define BAR_LGKM() do { \
    asm volatile("s_waitcnt lgkmcnt(0)" ::: "memory"); \
    __builtin_amdgcn_s_barrier(); \
} while (0)

// ---------------------------------------------------------------------------
// Kernel 1: prep = wcvt (blocks 0..255) + gn_stats (blocks 256..511).
// ---------------------------------------------------------------------------
__global__ __launch_bounds__(256) void prep_kernel(
    const float* __restrict__ wq, const float* __restrict__ wk,
    const float* __restrict__ wv, const float* __restrict__ wo,
    const float* __restrict__ x, u16* __restrict__ Wbf,
    float2* __restrict__ part) {
    int blk = blockIdx.x;
    int t = threadIdx.x;
    if (blk < 256) {
        int base = (blk * 256 + t) * 4;
        int p = base >> 16;
        int off = base & 65535;
        const float* W = (p == 0) ? wq : ((p == 1) ? wk : ((p == 2) ? wv : wo));
        float sc = (p == 0) ? 0.09014009048f : 1.0f;   // log2(e)/16
        float4 v = *(const float4*)(W + off);
        uint2 pk;
        pk.x = pkbf(v.x * sc, v.y * sc);
        pk.y = pkbf(v.z * sc, v.w * sc);
        *(uint2*)(Wbf + base) = pk;
        return;
    }
    int sblk = blk - 256;
    int bg = sblk >> 2, quarter = sblk & 3;
    const float* xp = x + (size_t)bg * 32768 + quarter * 8192;

    float s = 0.f, ss = 0.f;
#pragma unroll
    for (int rep = 0; rep < 8; ++rep) {
        float4 v = *(const float4*)(xp + t * 4 + rep * 1024);
        s += v.x + v.y + v.z + v.w;
        ss += v.x * v.x + v.y * v.y + v.z * v.z + v.w * v.w;
    }
    for (int off = 1; off < 64; off <<= 1) {
        s += __shfl_xor(s, off);
        ss += __shfl_xor(ss, off);
    }
    __shared__ float red[8];
    int lane = t & 63, w = t >> 6;
    if (lane == 0) { red[w] = s; red[4 + w] = ss; }
    __syncthreads();
    if (t == 0) {
        part[sblk] = make_float2(red[0] + red[1] + red[2] + red[3],
                                 red[4] + red[5] + red[6] + red[7]);
    }
}

// ---------------------------------------------------------------------------
// Kernel 2: QKV GEMM, fused GroupNorm B-stage. R23: double-buffered LDS +
// register prefetch (R14's proven attn pattern): next k-tile's global loads
// issue BEFORE the MFMA block, ds_writes to the idle buffer after, one
// BAR_LGKM per k-step — global latency hides under MFMA instead of being
// serially exposed at every iteration (the old load->sync->MFMA->sync had
// zero overlap). Coalesced B-stage layout (R21) retained.
// ---------------------------------------------------------------------------
__global__ __launch_bounds__(256) void qkv_gemm(
    const float* __restrict__ x, const float* __restrict__ gw,
    const float* __restrict__ gb, const float2* __restrict__ part,
    const u16* __restrict__ Wbf,
    u16* __restrict__ Q, u16* __restrict__ K, u16* __restrict__ V) {
    int b = blockIdx.y & 1;
    int p = blockIdx.y >> 1;
    const u16* W = Wbf + p * 65536;
    int m0 = (blockIdx.x & 1) * 128;
    int n0 = (blockIdx.x >> 1) * 64;

    __shared__ u16 a_s[2][128 * 40];
    __shared__ u16 b_s[2][64 * 40];
    __shared__ float wgt_s[256], bia_s[256];

    int t = threadIdx.x;
    int lane = t & 63, wave = t >> 6;
    int wm = wave & 1, wn = wave >> 1;
    int r = lane & 15, qd = lane >> 4;

    {
        int c = t;
        int g = c >> 3;
        float s = 0.f, ss = 0.f;
#pragma unroll
        for (int q = 0; q < 4; ++q) {
            float2 pp = part[(b * 32 + g) * 4 + q];
            s += pp.x; ss += pp.y;
        }
        float mu = s * (1.f / 32768.f);
        float var = ss * (1.f / 32768.f) - mu * mu;
        float rstd = rsqrtf(var + 1e-5f);
        float wg = gw[c] * rstd;
        wgt_s[c] = wg;
        bia_s[c] = gb[c] - mu * wg;
    }
    __syncthreads();

    f32x4 acc[4][2];
#pragma unroll
    for (int i = 0; i < 4; ++i)
#pragma unroll
        for (int j = 0; j < 2; ++j) acc[i][j] = (f32x4){0.f, 0.f, 0.f, 0.f};

    int srow = t >> 1;
    int scp = (t & 1) * 16;
    int bn = t & 63;                     // n within tile (lane -> coalesced)
    int bw = t >> 6;                     // wave = logical c-granule
    int bswz = ((bn >> 3) & 3) ^ (((bn >> 5) & 1) << 1);
    int bgp = ((bw ^ bswz) << 3);

    uint4 pa0, pa1;
    float pxv[8];
    auto load_regs = [&](int kk) {
        const u16* src = W + (m0 + srow) * 256 + kk + scp;
        pa0 = *(const uint4*)(src);
        pa1 = *(const uint4*)(src + 8);
        const float* xcol = x + (size_t)(b * 256 + kk + bw * 8) * 4096 + n0 + bn;
#pragma unroll
        for (int j = 0; j < 8; ++j) pxv[j] = xcol[(size_t)j * 4096];
    };
    auto write_buf = [&](int bsel, int kk) {
        *(uint4*)(a_s[bsel] + srow * 40 + scp) = pa0;
        *(uint4*)(a_s[bsel] + srow * 40 + scp + 8) = pa1;
#pragma unroll
        for (int j = 0; j < 8; ++j) {
            int c = kk + bw * 8 + j;
            b_s[bsel][bn * 40 + bgp + j] = f2bf(pxv[j] * wgt_s[c] + bia_s[c]);
        }
    };

    load_regs(0);
    write_buf(0, 0);
    BAR_LGKM();

    for (int it = 0; it < 8; ++it) {
        int cur = it & 1;
        bool more = (it + 1) < 8;
        if (more) load_regs((it + 1) * 32);

        bf16x8 af[4], bf[2];
#pragma unroll
        for (int mt = 0; mt < 4; ++mt)
            af[mt] = *(const bf16x8*)(a_s[cur] + (wm * 64 + mt * 16 + r) * 40 + qd * 8);
#pragma unroll
        for (int nt = 0; nt < 2; ++nt) {
            int row = wn * 32 + nt * 16 + r;
            int rswz = ((row >> 3) & 3) ^ (((row >> 5) & 1) << 1);
            bf[nt] = *(const bf16x8*)(b_s[cur] + row * 40 + ((qd ^ rswz) << 3));
        }
        if (p == 2) {
#pragma unroll
            for (int mt = 0; mt < 4; ++mt)
#pragma unroll
                for (int nt = 0; nt < 2; ++nt)
                    acc[mt][nt] = MFMA(bf[nt], af[mt], acc[mt][nt]);
        } else {
#pragma unroll
            for (int mt = 0; mt < 4; ++mt)
#pragma unroll
                for (int nt = 0; nt < 2; ++nt)
                    acc[mt][nt] = MFMA(af[mt], bf[nt], acc[mt][nt]);
        }

        if (more) write_buf(cur ^ 1, (it + 1) * 32);
        BAR_LGKM();
    }

    if (p < 2) {
        u16* dst = (p == 0) ? Q : K;
#pragma unroll
        for (int mt = 0; mt < 4; ++mt) {
#pragma unroll
            for (int nt = 0; nt < 2; ++nt) {
                int o0 = m0 + wm * 64 + mt * 16 + qd * 4;
                int s = n0 + wn * 32 + nt * 16 + r;
                int h = o0 >> 6, d0 = o0 & 63;
                uint2 pk;
                pk.x = pkbf(acc[mt][nt][0], acc[mt][nt][1]);
                pk.y = pkbf(acc[mt][nt][2], acc[mt][nt][3]);
                *(uint2*)(dst + ((size_t)((b * 4 + h) * 4096 + s)) * 64 + d0) = pk;
            }
        }
    } else {
#pragma unroll
        for (int mt = 0; mt < 4; ++mt) {
#pragma unroll
            for (int nt = 0; nt < 2; ++nt) {
                int o = m0 + wm * 64 + mt * 16 + r;
                int h = o >> 6, d = o & 63;
                int sb = n0 + wn * 32 + nt * 16 + qd * 4;
                uint2 pk;
                pk.x = pkbf(acc[mt][nt][0], acc[mt][nt][1]);
                pk.y = pkbf(acc[mt][nt][2], acc[mt][nt][3]);
                *(uint2*)(V + ((size_t)((b * 4 + h) * 64 + d)) * 4096 + sb) = pk;
            }
        }
    }
}

// ---------------------------------------------------------------------------
// Kernel 3: flash attention (R20/R21 structure, unchanged: QT=1 + DMA
// staging, 64 VGPR + 32 AGPR, 4 blocks/CU, nsplit=4).
// ---------------------------------------------------------------------------
template <int QT>
__global__ __launch_bounds__(256, QT == 1 ? 4 : 2) void attn_kernel(
    const u16* __restrict__ Q, const u16* __restrict__ K,
    const u16* __restrict__ V, u16* __restrict__ Opart,
    float* __restrict__ Lpart, int nk32) {
    int bh = blockIdx.x & 7, sp = blockIdx.x >> 3;
    int qb = blockIdx.y;
    int t = threadIdx.x, lane = t & 63, w = t >> 6;
    int qn = lane & 31, h = lane >> 5;

    const size_t bhoff = (size_t)bh * 4096 * 64;
    int q0 = (qb * 4 + w) * (32 * QT);
    int kbase = sp * nk32 * 32;

    __shared__ u16 smem[16384];

    bf16x8 qf[QT][4];
#pragma unroll
    for (int qt = 0; qt < QT; ++qt)
#pragma unroll
        for (int c = 0; c < 4; ++c)
            qf[qt][c] = *(const bf16x8*)(Q + bhoff +
                (size_t)(q0 + qt * 32 + qn) * 64 + c * 16 + h * 8);

    f32x16 oacc[2][QT];
#pragma unroll
    for (int dt = 0; dt < 2; ++dt)
#pragma unroll
        for (int qt = 0; qt < QT; ++qt)
#pragma unroll
            for (int i = 0; i < 16; ++i) oacc[dt][qt][i] = 0.f;
    float lacc[QT];
#pragma unroll
    for (int qt = 0; qt < QT; ++qt) lacc[qt] = 0.f;

    const u16* Kp = K + bhoff;
    const u16* Vp = V + bhoff;

    int gs = (lane & 7) ^ (lane >> 3);
    int rbase = (w & 1) * 32 + (lane >> 3);

    auto fill = [&](int bufsel, int kp) {
        u16* ld = smem + bufsel * 8192 + w * 2048;
        if (w < 2) {
            const u16* s = Kp + (size_t)(kp + rbase) * 64 + gs * 8;
#pragma unroll
            for (int j = 0; j < 4; ++j) gll16(s + j * 512, ld + j * 512);
        } else {
            const u16* s = Vp + (size_t)rbase * 4096 + kp + gs * 8;
#pragma unroll
            for (int j = 0; j < 4; ++j) gll16(s + j * 32768, ld + j * 512);
        }
    };

    int sw = qn & 7;
    auto step = [&](const u16* buf, int j) {
        bf16x8 kf[4], vf[2][2];
        int kr = j * 32 + qn;
#pragma unroll
        for (int c = 0; c < 4; ++c)
            kf[c] = *(const bf16x8*)(buf + kr * 64 + (((c * 2 + h) ^ sw) << 3));
#pragma unroll
        for (int dt = 0; dt < 2; ++dt) {
            int d = dt * 32 + qn;
#pragma unroll
            for (int kc = 0; kc < 2; ++kc) {
                int g = j * 4 + kc * 2 + h;
                vf[dt][kc] = *(const bf16x8*)(buf + 4096 + d * 64 + ((g ^ sw) << 3));
            }
        }
#pragma unroll
        for (int qt = 0; qt < QT; ++qt) {
            f32x16 s;
#pragma unroll
            for (int i = 0; i < 16; ++i) s[i] = 0.f;
            __builtin_amdgcn_s_setprio(1);
#pragma unroll
            for (int c = 0; c < 4; ++c) s = MFMA32(kf[c], qf[qt][c], s);
            __builtin_amdgcn_s_setprio(0);

            float e[16];
#pragma unroll
            for (int i = 0; i < 16; ++i)
                e[i] = __builtin_amdgcn_exp2f(s[i]);
            float t0 = (e[0] + e[1]) + (e[2] + e[3]);
            float t1 = (e[4] + e[5]) + (e[6] + e[7]);
            float t2 = (e[8] + e[9]) + (e[10] + e[11]);
            float t3 = (e[12] + e[13]) + (e[14] + e[15]);
            lacc[qt] += (t0 + t1) + (t2 + t3);

            u32 p[8];
#pragma unroll
            for (int i = 0; i < 8; ++i) p[i] = pkbf(e[2 * i], e[2 * i + 1]);

            u32x2 r0 = __builtin_amdgcn_permlane32_swap(p[0], p[2], false, false);
            u32x2 r1 = __builtin_amdgcn_permlane32_swap(p[1], p[3], false, false);
            u32x2 r2 = __builtin_amdgcn_permlane32_swap(p[4], p[6], false, false);
            u32x2 r3 = __builtin_amdgcn_permlane32_swap(p[5], p[7], false, false);
            uint4 pau = {r0[0], r1[0], r0[1], r1[1]};
            uint4 pbu = {r2[0], r3[0], r2[1], r3[1]};
            bf16x8 pA = *(const bf16x8*)&pau;
            bf16x8 pB = *(const bf16x8*)&pbu;

            __builtin_amdgcn_s_setprio(1);
#pragma unroll
            for (int dt = 0; dt < 2; ++dt) {
                oacc[dt][qt] = MFMA32(vf[dt][0], pA, oacc[dt][qt]);
                oacc[dt][qt] = MFMA32(vf[dt][1], pB, oacc[dt][qt]);
            }
            __builtin_amdgcn_s_setprio(0);
        }
    };

    int npair = nk32 >> 1;
    fill(0, kbase);
    if (npair > 1) fill(1, kbase + 64);
    BAR_VM();

    for (int i = 0; i < npair; ++i) {
        const u16* cur = smem + (i & 1) * 8192;
        step(cur, 0);
        step(cur, 1);
        BAR_VM();
        if (i + 2 < npair) fill(i & 1, kbase + (i + 2) * 64);
    }

    float lfull[QT];
#pragma unroll
    for (int qt = 0; qt < QT; ++qt)
        lfull[qt] = lacc[qt] + __shfl_xor(lacc[qt], 32);

    u16* my = smem + w * (32 * 72);
    size_t obase = ((size_t)sp * 8 + bh) * 4096 + q0;
#pragma unroll
    for (int qt = 0; qt < QT; ++qt) {
#pragma unroll
        for (int dt = 0; dt < 2; ++dt) {
#pragma unroll
            for (int g = 0; g < 4; ++g) {
                int d0 = g * 8 + h * 4 + dt * 32;
                uint2 pk;
                pk.x = pkbf(oacc[dt][qt][4 * g], oacc[dt][qt][4 * g + 1]);
                pk.y = pkbf(oacc[dt][qt][4 * g + 2], oacc[dt][qt][4 * g + 3]);
                *(uint2*)(my + qn * 72 + d0) = pk;
            }
        }
#pragma unroll
        for (int rr = 0; rr < 4; ++rr) {
            int row = rr * 8 + (lane >> 3), ch = lane & 7;
            uint4 v = *(const uint4*)(my + row * 72 + ch * 8);
            *(uint4*)(Opart + (obase + qt * 32 + row) * 64 + ch * 8) = v;
        }
    }
    if (h == 0) {
#pragma unroll
        for (int qt = 0; qt < QT; ++qt)
            Lpart[obase + qt * 32 + qn] = lfull[qt];
    }
}

// ---------------------------------------------------------------------------
// Kernel 4: combine nsplit partials, normalize, write attnT[b][s][c] bf16.
// (R21 version restored — R22's fusion into out_gemm cost +15us.)
// ---------------------------------------------------------------------------
__global__ __launch_bounds__(256) void attn_combine(
    const u16* __restrict__ Opart, const float* __restrict__ Lpart,
    u16* __restrict__ attnT, int nsplit) {
    int t = threadIdx.x;
    int gr = blockIdx.x * 64 + (t >> 2);      // bh*4096+q
    int d0 = (t & 3) * 16;

    float l = 0.f;
    for (int s = 0; s < nsplit; ++s) l += Lpart[(size_t)s * 32768 + gr];
    float inv = 1.f / l;

    float acc[16];
#pragma unroll
    for (int i = 0; i < 16; ++i) acc[i] = 0.f;
    for (int s = 0; s < nsplit; ++s) {
        const u16* p = Opart + ((size_t)s * 32768 + gr) * 64 + d0;
        uint4 a = *(const uint4*)(p);
        uint4 bq = *(const uint4*)(p + 8);
        const u32* ap = (const u32*)&a;
        const u32* bp = (const u32*)&bq;
#pragma unroll
        for (int j = 0; j < 4; ++j) {
            acc[2 * j]     += __uint_as_float(ap[j] << 16);
            acc[2 * j + 1] += __uint_as_float(ap[j] & 0xFFFF0000u);
            acc[8 + 2 * j]     += __uint_as_float(bp[j] << 16);
            acc[8 + 2 * j + 1] += __uint_as_float(bp[j] & 0xFFFF0000u);
        }
    }
    u32 pk[8];
#pragma unroll
    for (int j = 0; j < 8; ++j)
        pk[j] = pkbf(acc[2 * j] * inv, acc[2 * j + 1] * inv);

    int bh = gr >> 12, q = gr & 4095;
    int b = bh >> 2, hh = bh & 3;
    u16* dst = attnT + ((size_t)(b * 4096 + q)) * 256 + hh * 64 + d0;
    *(uint4*)(dst) = make_uint4(pk[0], pk[1], pk[2], pk[3]);
    *(uint4*)(dst + 8) = make_uint4(pk[4], pk[5], pk[6], pk[7]);
}

// ---------------------------------------------------------------------------
// Kernel 5: output GEMM + bias + residual. R23: 64x64 tiles, grid (256,2),
// double-buffered LDS + register prefetch (same pattern as qkv).
// ---------------------------------------------------------------------------
__global__ __launch_bounds__(256) void out_gemm(
    const u16* __restrict__ attnT, const u16* __restrict__ W3,
    const float* __restrict__ bo, const float* __restrict__ x,
    float* __restrict__ out) {
    int b = blockIdx.y;
    int m0 = (blockIdx.x & 3) * 64;
    int n0 = (blockIdx.x >> 2) * 64;

    __shared__ u16 a_s[2][64 * 40];
    __shared__ u16 b_s[2][64 * 40];

    int t = threadIdx.x;
    int lane = t & 63, wave = t >> 6;
    int wm = wave & 1, wn = wave >> 1;
    int r = lane & 15, qd = lane >> 4;

    const u16* Bsrc = attnT + (size_t)b * 4096 * 256;

    f32x4 acc[2][2];
#pragma unroll
    for (int i = 0; i < 2; ++i)
#pragma unroll
        for (int j = 0; j < 2; ++j) acc[i][j] = (f32x4){0.f, 0.f, 0.f, 0.f};

    int u = t & 127;
    int srow = u >> 1;
    int scp = (u & 1) * 16;

    uint4 p0, p1;
    auto load_regs = [&](int kk) {
        const u16* src = (t < 128)
            ? W3 + (m0 + srow) * 256 + kk + scp
            : Bsrc + (size_t)(n0 + srow) * 256 + kk + scp;
        p0 = *(const uint4*)(src);
        p1 = *(const uint4*)(src + 8);
    };
    auto write_buf = [&](int bsel) {
        u16* dst = (t < 128) ? (a_s[bsel] + srow * 40 + scp)
                             : (b_s[bsel] + srow * 40 + scp);
        *(uint4*)(dst) = p0;
        *(uint4*)(dst + 8) = p1;
    };

    load_regs(0);
    write_buf(0);
    BAR_LGKM();

    for (int it = 0; it < 8; ++it) {
        int cur = it & 1;
        bool more = (it + 1) < 8;
        if (more) load_regs((it + 1) * 32);

        bf16x8 af[2], bf[2];
#pragma unroll
        for (int mt = 0; mt < 2; ++mt)
            af[mt] = *(const bf16x8*)(a_s[cur] + (wm * 32 + mt * 16 + r) * 40 + qd * 8);
#pragma unroll
        for (int nt = 0; nt < 2; ++nt)
            bf[nt] = *(const bf16x8*)(b_s[cur] + (wn * 32 + nt * 16 + r) * 40 + qd * 8);
#pragma unroll
        for (int mt = 0; mt < 2; ++mt)
#pragma unroll
            for (int nt = 0; nt < 2; ++nt)
                acc[mt][nt] = MFMA(af[mt], bf[nt], acc[mt][nt]);

        if (more) write_buf(cur ^ 1);
        BAR_LGKM();
    }

#pragma unroll
    for (int mt = 0; mt < 2; ++mt) {
#pragma unroll
        for (int nt = 0; nt < 2; ++nt) {
#pragma unroll
            for (int j = 0; j < 4; ++j) {
                int o = m0 + wm * 32 + mt * 16 + qd * 4 + j;
                int s = n0 + wn * 32 + nt * 16 + r;
                size_t idx = (size_t)(b * 256 + o) * 4096 + s;
                out[idx] = acc[mt][nt][j] + bo[o] + x[idx];
            }
        }
    }
}

// ---------------------------------------------------------------------------
extern "C" void kernel_launch(void* const* d_in, const int* in_sizes, int n_in,
                              void* d_out, int out_size, void* d_ws, size_t ws_size,
                              hipStream_t stream) {
    const float* x = (const float*)d_in[0];
    const float* gn_w = (const float*)d_in[1];
    const float* gn_b = (const float*)d_in[2];
    const float* wq = (const float*)d_in[3];
    const float* wk = (const float*)d_in[4];
    const float* wv = (const float*)d_in[5];
    const float* wo = (const float*)d_in[6];
    const float* bo = (const float*)d_in[7];
    float* out = (float*)d_out;

    char* ws = (char*)d_ws;
    u16* attnT = (u16*)(ws);                        // [0,4M)
    u16* Q     = (u16*)(ws + (4u << 20));           // [b][h][s][d] (scaled log2e/16)
    u16* Kp    = (u16*)(ws + (8u << 20));           // [b][h][s][d]
    u16* Vp    = (u16*)(ws + (12u << 20));          // [b][h][d][s]
    u16* Wbf   = (u16*)(ws + (16u << 20));          // 512 KB
    float2* part = (float2*)(ws + (16u << 20) + 524288);

    size_t opart_off = (size_t)17 << 20;
    size_t osplit = 8ull * 4096 * 64 * 2;            // 4 MB per split
    int nsplit = (ws_size >= opart_off + 4 * osplit + 4ull * 32768 * 4 + 4096) ? 4 : 2;
    u16* Opart = (u16*)(ws + opart_off);
    float* Lpart = (float*)(ws + opart_off + (size_t)nsplit * osplit);

    prep_kernel<<<512, 256, 0, stream>>>(wq, wk, wv, wo, x, Wbf, part);
    qkv_gemm<<<dim3(128, 6), 256, 0, stream>>>(x, gn_w, gn_b, part, Wbf, Q, Kp, Vp);
    attn_kernel<1><<<dim3(8 * nsplit, 32), 256, 0, stream>>>(
        Q, Kp, Vp, Opart, Lpart, 128 / nsplit);
    attn_combine<<<512, 256, 0, stream>>>(Opart, Lpart, attnT, nsplit);
    out_gemm<<<dim3(256, 2), 256, 0, stream>>>(attnT, Wbf + 3 * 65536, bo, x, out);
}

// Round 12
// 139.781 us; speedup vs baseline: 1.1313x; 1.0003x over previous
//
#include <hip/hip_runtime.h>

typedef float f32x4 __attribute__((ext_vector_type(4)));
typedef float f32x16 __attribute__((ext_vector_type(16)));
typedef short bf16x8 __attribute__((ext_vector_type(8)));
typedef unsigned short u16;
typedef unsigned int u32;
typedef unsigned int u32x2 __attribute__((ext_vector_type(2)));

#define MFMA(a, b, c) __builtin_amdgcn_mfma_f32_16x16x32_bf16((a), (b), (c), 0, 0, 0)
#define MFMA32(a, b, c) __builtin_amdgcn_mfma_f32_32x32x16_bf16((a), (b), (c), 0, 0, 0)

static __device__ __forceinline__ u16 f2bf(float f) {
    union { float f; u32 u; } v; v.f = f;
    u32 r = v.u + 0x7FFFu + ((v.u >> 16) & 1u);
    return (u16)(r >> 16);
}

// pack two fp32 -> two bf16 in one u32 (a low, b high)
static __device__ __forceinline__ u32 pkbf(float a, float b) {
    u32 ua = __float_as_uint(a) + 0x8000u;
    u32 ub = __float_as_uint(b) + 0x8000u;
    return __builtin_amdgcn_perm(ub, ua, 0x07060302);
}

// async global->LDS DMA, 16B per lane: LDS dest = wave-uniform base + lane*16.
static __device__ __forceinline__ void gll16(const u16* g, u16* l) {
    __builtin_amdgcn_global_load_lds(
        (const __attribute__((address_space(1))) u32*)(const void*)g,
        (__attribute__((address_space(3))) u32*)(void*)l, 16, 0, 0);
}

// barrier with vmcnt drain (DMA fills tracked by vmcnt).
#define BAR_VM() do { \
    asm volatile("s_waitcnt vmcnt(0)" ::: "memory"); \
    __builtin_amdgcn_s_barrier(); \
    asm volatile("" ::: "memory"); \
} while (0)

// barrier draining only LDS ops; in-flight global loads may cross (their
// data is consumed at the register-use site via compiler vmcnt waits).
#define BAR_LGKM() do { \
    asm volatile("s_waitcnt lgkmcnt(0)" ::: "memory"); \
    __builtin_amdgcn_s_barrier(); \
} while (0)

// ---------------------------------------------------------------------------
// Kernel 1: prep = wcvt (blocks 0..255) + gn_stats (blocks 256..511).
// ---------------------------------------------------------------------------
__global__ __launch_bounds__(256) void prep_kernel(
    const float* __restrict__ wq, const float* __restrict__ wk,
    const float* __restrict__ wv, const float* __restrict__ wo,
    const float* __restrict__ x, u16* __restrict__ Wbf,
    float2* __restrict__ part) {
    int blk = blockIdx.x;
    int t = threadIdx.x;
    if (blk < 256) {
        int base = (blk * 256 + t) * 4;
        int p = base >> 16;
        int off = base & 65535;
        const float* W = (p == 0) ? wq : ((p == 1) ? wk : ((p == 2) ? wv : wo));
        float sc = (p == 0) ? 0.09014009048f : 1.0f;   // log2(e)/16
        float4 v = *(const float4*)(W + off);
        uint2 pk;
        pk.x = pkbf(v.x * sc, v.y * sc);
        pk.y = pkbf(v.z * sc, v.w * sc);
        *(uint2*)(Wbf + base) = pk;
        return;
    }
    int sblk = blk - 256;
    int bg = sblk >> 2, quarter = sblk & 3;
    const float* xp = x + (size_t)bg * 32768 + quarter * 8192;

    float s = 0.f, ss = 0.f;
#pragma unroll
    for (int rep = 0; rep < 8; ++rep) {
        float4 v = *(const float4*)(xp + t * 4 + rep * 1024);
        s += v.x + v.y + v.z + v.w;
        ss += v.x * v.x + v.y * v.y + v.z * v.z + v.w * v.w;
    }
    for (int off = 1; off < 64; off <<= 1) {
        s += __shfl_xor(s, off);
        ss += __shfl_xor(ss, off);
    }
    __shared__ float red[8];
    int lane = t & 63, w = t >> 6;
    if (lane == 0) { red[w] = s; red[4 + w] = ss; }
    __syncthreads();
    if (t == 0) {
        part[sblk] = make_float2(red[0] + red[1] + red[2] + red[3],
                                 red[4] + red[5] + red[6] + red[7]);
    }
}

// ---------------------------------------------------------------------------
// Kernel 2: QKV GEMM, fused GroupNorm B-stage. R24:
// (a) B-stage stores 4x pkbf u32 instead of 8x f2bf u16: staging VALU cut
//     ~2.5x (B-stage was ~100cy/wave vs ~40cy MFMA — VALU paced the loop).
// (b) XCD co-location: the two m0-blocks sharing an x-tile now differ by 8
//     in blockIdx.x (same XCD under round-robin) -> x-tile L2-shared
//     instead of double-fetched from L3. bx bits: [2:0]=n_lo [3]=m [6:4]=n_hi.
// Double-buffer + register prefetch (R23) retained.
// ---------------------------------------------------------------------------
__global__ __launch_bounds__(256) void qkv_gemm(
    const float* __restrict__ x, const float* __restrict__ gw,
    const float* __restrict__ gb, const float2* __restrict__ part,
    const u16* __restrict__ Wbf,
    u16* __restrict__ Q, u16* __restrict__ K, u16* __restrict__ V) {
    int b = blockIdx.y & 1;
    int p = blockIdx.y >> 1;
    const u16* W = Wbf + p * 65536;
    int bx = blockIdx.x;
    int m0 = ((bx >> 3) & 1) * 128;
    int n0 = ((bx & 7) | ((bx >> 4) << 3)) * 64;

    __shared__ u16 a_s[2][128 * 40];
    __shared__ u16 b_s[2][64 * 40];
    __shared__ float wgt_s[256], bia_s[256];

    int t = threadIdx.x;
    int lane = t & 63, wave = t >> 6;
    int wm = wave & 1, wn = wave >> 1;
    int r = lane & 15, qd = lane >> 4;

    {
        int c = t;
        int g = c >> 3;
        float s = 0.f, ss = 0.f;
#pragma unroll
        for (int q = 0; q < 4; ++q) {
            float2 pp = part[(b * 32 + g) * 4 + q];
            s += pp.x; ss += pp.y;
        }
        float mu = s * (1.f / 32768.f);
        float var = ss * (1.f / 32768.f) - mu * mu;
        float rstd = rsqrtf(var + 1e-5f);
        float wg = gw[c] * rstd;
        wgt_s[c] = wg;
        bia_s[c] = gb[c] - mu * wg;
    }
    __syncthreads();

    f32x4 acc[4][2];
#pragma unroll
    for (int i = 0; i < 4; ++i)
#pragma unroll
        for (int j = 0; j < 2; ++j) acc[i][j] = (f32x4){0.f, 0.f, 0.f, 0.f};

    int srow = t >> 1;
    int scp = (t & 1) * 16;
    int bn = t & 63;                     // n within tile (lane -> coalesced)
    int bw = t >> 6;                     // wave = logical c-granule
    int bswz = ((bn >> 3) & 3) ^ (((bn >> 5) & 1) << 1);
    int bgp = ((bw ^ bswz) << 3);

    uint4 pa0, pa1;
    float pxv[8];
    auto load_regs = [&](int kk) {
        const u16* src = W + (m0 + srow) * 256 + kk + scp;
        pa0 = *(const uint4*)(src);
        pa1 = *(const uint4*)(src + 8);
        const float* xcol = x + (size_t)(b * 256 + kk + bw * 8) * 4096 + n0 + bn;
#pragma unroll
        for (int j = 0; j < 8; ++j) pxv[j] = xcol[(size_t)j * 4096];
    };
    auto write_buf = [&](int bsel, int kk) {
        *(uint4*)(a_s[bsel] + srow * 40 + scp) = pa0;
        *(uint4*)(a_s[bsel] + srow * 40 + scp + 8) = pa1;
        u32* dst = (u32*)(b_s[bsel] + bn * 40 + bgp);
#pragma unroll
        for (int j = 0; j < 4; ++j) {
            int c = kk + bw * 8 + 2 * j;
            dst[j] = pkbf(pxv[2 * j] * wgt_s[c] + bia_s[c],
                          pxv[2 * j + 1] * wgt_s[c + 1] + bia_s[c + 1]);
        }
    };

    load_regs(0);
    write_buf(0, 0);
    BAR_LGKM();

    for (int it = 0; it < 8; ++it) {
        int cur = it & 1;
        bool more = (it + 1) < 8;
        if (more) load_regs((it + 1) * 32);

        bf16x8 af[4], bf[2];
#pragma unroll
        for (int mt = 0; mt < 4; ++mt)
            af[mt] = *(const bf16x8*)(a_s[cur] + (wm * 64 + mt * 16 + r) * 40 + qd * 8);
#pragma unroll
        for (int nt = 0; nt < 2; ++nt) {
            int row = wn * 32 + nt * 16 + r;
            int rswz = ((row >> 3) & 3) ^ (((row >> 5) & 1) << 1);
            bf[nt] = *(const bf16x8*)(b_s[cur] + row * 40 + ((qd ^ rswz) << 3));
        }
        if (p == 2) {
#pragma unroll
            for (int mt = 0; mt < 4; ++mt)
#pragma unroll
                for (int nt = 0; nt < 2; ++nt)
                    acc[mt][nt] = MFMA(bf[nt], af[mt], acc[mt][nt]);
        } else {
#pragma unroll
            for (int mt = 0; mt < 4; ++mt)
#pragma unroll
                for (int nt = 0; nt < 2; ++nt)
                    acc[mt][nt] = MFMA(af[mt], bf[nt], acc[mt][nt]);
        }

        if (more) write_buf(cur ^ 1, (it + 1) * 32);
        BAR_LGKM();
    }

    if (p < 2) {
        u16* dst = (p == 0) ? Q : K;
#pragma unroll
        for (int mt = 0; mt < 4; ++mt) {
#pragma unroll
            for (int nt = 0; nt < 2; ++nt) {
                int o0 = m0 + wm * 64 + mt * 16 + qd * 4;
                int s = n0 + wn * 32 + nt * 16 + r;
                int h = o0 >> 6, d0 = o0 & 63;
                uint2 pk;
                pk.x = pkbf(acc[mt][nt][0], acc[mt][nt][1]);
                pk.y = pkbf(acc[mt][nt][2], acc[mt][nt][3]);
                *(uint2*)(dst + ((size_t)((b * 4 + h) * 4096 + s)) * 64 + d0) = pk;
            }
        }
    } else {
#pragma unroll
        for (int mt = 0; mt < 4; ++mt) {
#pragma unroll
            for (int nt = 0; nt < 2; ++nt) {
                int o = m0 + wm * 64 + mt * 16 + r;
                int h = o >> 6, d = o & 63;
                int sb = n0 + wn * 32 + nt * 16 + qd * 4;
                uint2 pk;
                pk.x = pkbf(acc[mt][nt][0], acc[mt][nt][1]);
                pk.y = pkbf(acc[mt][nt][2], acc[mt][nt][3]);
                *(uint2*)(V + ((size_t)((b * 4 + h) * 64 + d)) * 4096 + sb) = pk;
            }
        }
    }
}

// ---------------------------------------------------------------------------
// Kernel 3: flash attention (R20/R21 structure, unchanged: QT=1 + DMA
// staging, 64 VGPR + 32 AGPR, 4 blocks/CU, nsplit=4).
// ---------------------------------------------------------------------------
template <int QT>
__global__ __launch_bounds__(256, QT == 1 ? 4 : 2) void attn_kernel(
    const u16* __restrict__ Q, const u16* __restrict__ K,
    const u16* __restrict__ V, u16* __restrict__ Opart,
    float* __restrict__ Lpart, int nk32) {
    int bh = blockIdx.x & 7, sp = blockIdx.x >> 3;
    int qb = blockIdx.y;
    int t = threadIdx.x, lane = t & 63, w = t >> 6;
    int qn = lane & 31, h = lane >> 5;

    const size_t bhoff = (size_t)bh * 4096 * 64;
    int q0 = (qb * 4 + w) * (32 * QT);
    int kbase = sp * nk32 * 32;

    __shared__ u16 smem[16384];

    bf16x8 qf[QT][4];
#pragma unroll
    for (int qt = 0; qt < QT; ++qt)
#pragma unroll
        for (int c = 0; c < 4; ++c)
            qf[qt][c] = *(const bf16x8*)(Q + bhoff +
                (size_t)(q0 + qt * 32 + qn) * 64 + c * 16 + h * 8);

    f32x16 oacc[2][QT];
#pragma unroll
    for (int dt = 0; dt < 2; ++dt)
#pragma unroll
        for (int qt = 0; qt < QT; ++qt)
#pragma unroll
            for (int i = 0; i < 16; ++i) oacc[dt][qt][i] = 0.f;
    float lacc[QT];
#pragma unroll
    for (int qt = 0; qt < QT; ++qt) lacc[qt] = 0.f;

    const u16* Kp = K + bhoff;
    const u16* Vp = V + bhoff;

    int gs = (lane & 7) ^ (lane >> 3);
    int rbase = (w & 1) * 32 + (lane >> 3);

    auto fill = [&](int bufsel, int kp) {
        u16* ld = smem + bufsel * 8192 + w * 2048;
        if (w < 2) {
            const u16* s = Kp + (size_t)(kp + rbase) * 64 + gs * 8;
#pragma unroll
            for (int j = 0; j < 4; ++j) gll16(s + j * 512, ld + j * 512);
        } else {
            const u16* s = Vp + (size_t)rbase * 4096 + kp + gs * 8;
#pragma unroll
            for (int j = 0; j < 4; ++j) gll16(s + j * 32768, ld + j * 512);
        }
    };

    int sw = qn & 7;
    auto step = [&](const u16* buf, int j) {
        bf16x8 kf[4], vf[2][2];
        int kr = j * 32 + qn;
#pragma unroll
        for (int c = 0; c < 4; ++c)
            kf[c] = *(const bf16x8*)(buf + kr * 64 + (((c * 2 + h) ^ sw) << 3));
#pragma unroll
        for (int dt = 0; dt < 2; ++dt) {
            int d = dt * 32 + qn;
#pragma unroll
            for (int kc = 0; kc < 2; ++kc) {
                int g = j * 4 + kc * 2 + h;
                vf[dt][kc] = *(const bf16x8*)(buf + 4096 + d * 64 + ((g ^ sw) << 3));
            }
        }
#pragma unroll
        for (int qt = 0; qt < QT; ++qt) {
            f32x16 s;
#pragma unroll
            for (int i = 0; i < 16; ++i) s[i] = 0.f;
            __builtin_amdgcn_s_setprio(1);
#pragma unroll
            for (int c = 0; c < 4; ++c) s = MFMA32(kf[c], qf[qt][c], s);
            __builtin_amdgcn_s_setprio(0);

            float e[16];
#pragma unroll
            for (int i = 0; i < 16; ++i)
                e[i] = __builtin_amdgcn_exp2f(s[i]);
            float t0 = (e[0] + e[1]) + (e[2] + e[3]);
            float t1 = (e[4] + e[5]) + (e[6] + e[7]);
            float t2 = (e[8] + e[9]) + (e[10] + e[11]);
            float t3 = (e[12] + e[13]) + (e[14] + e[15]);
            lacc[qt] += (t0 + t1) + (t2 + t3);

            u32 p[8];
#pragma unroll
            for (int i = 0; i < 8; ++i) p[i] = pkbf(e[2 * i], e[2 * i + 1]);

            u32x2 r0 = __builtin_amdgcn_permlane32_swap(p[0], p[2], false, false);
            u32x2 r1 = __builtin_amdgcn_permlane32_swap(p[1], p[3], false, false);
            u32x2 r2 = __builtin_amdgcn_permlane32_swap(p[4], p[6], false, false);
            u32x2 r3 = __builtin_amdgcn_permlane32_swap(p[5], p[7], false, false);
            uint4 pau = {r0[0], r1[0], r0[1], r1[1]};
            uint4 pbu = {r2[0], r3[0], r2[1], r3[1]};
            bf16x8 pA = *(const bf16x8*)&pau;
            bf16x8 pB = *(const bf16x8*)&pbu;

            __builtin_amdgcn_s_setprio(1);
#pragma unroll
            for (int dt = 0; dt < 2; ++dt) {
                oacc[dt][qt] = MFMA32(vf[dt][0], pA, oacc[dt][qt]);
                oacc[dt][qt] = MFMA32(vf[dt][1], pB, oacc[dt][qt]);
            }
            __builtin_amdgcn_s_setprio(0);
        }
    };

    int npair = nk32 >> 1;
    fill(0, kbase);
    if (npair > 1) fill(1, kbase + 64);
    BAR_VM();

    for (int i = 0; i < npair; ++i) {
        const u16* cur = smem + (i & 1) * 8192;
        step(cur, 0);
        step(cur, 1);
        BAR_VM();
        if (i + 2 < npair) fill(i & 1, kbase + (i + 2) * 64);
    }

    float lfull[QT];
#pragma unroll
    for (int qt = 0; qt < QT; ++qt)
        lfull[qt] = lacc[qt] + __shfl_xor(lacc[qt], 32);

    u16* my = smem + w * (32 * 72);
    size_t obase = ((size_t)sp * 8 + bh) * 4096 + q0;
#pragma unroll
    for (int qt = 0; qt < QT; ++qt) {
#pragma unroll
        for (int dt = 0; dt < 2; ++dt) {
#pragma unroll
            for (int g = 0; g < 4; ++g) {
                int d0 = g * 8 + h * 4 + dt * 32;
                uint2 pk;
                pk.x = pkbf(oacc[dt][qt][4 * g], oacc[dt][qt][4 * g + 1]);
                pk.y = pkbf(oacc[dt][qt][4 * g + 2], oacc[dt][qt][4 * g + 3]);
                *(uint2*)(my + qn * 72 + d0) = pk;
            }
        }
#pragma unroll
        for (int rr = 0; rr < 4; ++rr) {
            int row = rr * 8 + (lane >> 3), ch = lane & 7;
            uint4 v = *(const uint4*)(my + row * 72 + ch * 8);
            *(uint4*)(Opart + (obase + qt * 32 + row) * 64 + ch * 8) = v;
        }
    }
    if (h == 0) {
#pragma unroll
        for (int qt = 0; qt < QT; ++qt)
            Lpart[obase + qt * 32 + qn] = lfull[qt];
    }
}

// ---------------------------------------------------------------------------
// Kernel 4: combine nsplit partials, normalize, write attnT[b][s][c] bf16.
// ---------------------------------------------------------------------------
__global__ __launch_bounds__(256) void attn_combine(
    const u16* __restrict__ Opart, const float* __restrict__ Lpart,
    u16* __restrict__ attnT, int nsplit) {
    int t = threadIdx.x;
    int gr = blockIdx.x * 64 + (t >> 2);      // bh*4096+q
    int d0 = (t & 3) * 16;

    float l = 0.f;
    for (int s = 0; s < nsplit; ++s) l += Lpart[(size_t)s * 32768 + gr];
    float inv = 1.f / l;

    float acc[16];
#pragma unroll
    for (int i = 0; i < 16; ++i) acc[i] = 0.f;
    for (int s = 0; s < nsplit; ++s) {
        const u16* p = Opart + ((size_t)s * 32768 + gr) * 64 + d0;
        uint4 a = *(const uint4*)(p);
        uint4 bq = *(const uint4*)(p + 8);
        const u32* ap = (const u32*)&a;
        const u32* bp = (const u32*)&bq;
#pragma unroll
        for (int j = 0; j < 4; ++j) {
            acc[2 * j]     += __uint_as_float(ap[j] << 16);
            acc[2 * j + 1] += __uint_as_float(ap[j] & 0xFFFF0000u);
            acc[8 + 2 * j]     += __uint_as_float(bp[j] << 16);
            acc[8 + 2 * j + 1] += __uint_as_float(bp[j] & 0xFFFF0000u);
        }
    }
    u32 pk[8];
#pragma unroll
    for (int j = 0; j < 8; ++j)
        pk[j] = pkbf(acc[2 * j] * inv, acc[2 * j + 1] * inv);

    int bh = gr >> 12, q = gr & 4095;
    int b = bh >> 2, hh = bh & 3;
    u16* dst = attnT + ((size_t)(b * 4096 + q)) * 256 + hh * 64 + d0;
    *(uint4*)(dst) = make_uint4(pk[0], pk[1], pk[2], pk[3]);
    *(uint4*)(dst + 8) = make_uint4(pk[4], pk[5], pk[6], pk[7]);
}

// ---------------------------------------------------------------------------
// Kernel 5: output GEMM + bias + residual. R24: XCD co-location — the four
// m0-blocks sharing a B-panel (attnT n-slice) now differ by 8 in blockIdx.x
// (same XCD). bx bits: [2:0]=n_lo [4:3]=m [7:5]=n_hi. Double-buffer (R23)
// retained.
// ---------------------------------------------------------------------------
__global__ __launch_bounds__(256) void out_gemm(
    const u16* __restrict__ attnT, const u16* __restrict__ W3,
    const float* __restrict__ bo, const float* __restrict__ x,
    float* __restrict__ out) {
    int b = blockIdx.y;
    int bx = blockIdx.x;
    int m0 = ((bx >> 3) & 3) * 64;
    int n0 = ((bx & 7) | ((bx >> 5) << 3)) * 64;

    __shared__ u16 a_s[2][64 * 40];
    __shared__ u16 b_s[2][64 * 40];

    int t = threadIdx.x;
    int lane = t & 63, wave = t >> 6;
    int wm = wave & 1, wn = wave >> 1;
    int r = lane & 15, qd = lane >> 4;

    const u16* Bsrc = attnT + (size_t)b * 4096 * 256;

    f32x4 acc[2][2];
#pragma unroll
    for (int i = 0; i < 2; ++i)
#pragma unroll
        for (int j = 0; j < 2; ++j) acc[i][j] = (f32x4){0.f, 0.f, 0.f, 0.f};

    int u = t & 127;
    int srow = u >> 1;
    int scp = (u & 1) * 16;

    uint4 p0, p1;
    auto load_regs = [&](int kk) {
        const u16* src = (t < 128)
            ? W3 + (m0 + srow) * 256 + kk + scp
            : Bsrc + (size_t)(n0 + srow) * 256 + kk + scp;
        p0 = *(const uint4*)(src);
        p1 = *(const uint4*)(src + 8);
    };
    auto write_buf = [&](int bsel) {
        u16* dst = (t < 128) ? (a_s[bsel] + srow * 40 + scp)
                             : (b_s[bsel] + srow * 40 + scp);
        *(uint4*)(dst) = p0;
        *(uint4*)(dst + 8) = p1;
    };

    load_regs(0);
    write_buf(0);
    BAR_LGKM();

    for (int it = 0; it < 8; ++it) {
        int cur = it & 1;
        bool more = (it + 1) < 8;
        if (more) load_regs((it + 1) * 32);

        bf16x8 af[2], bf[2];
#pragma unroll
        for (int mt = 0; mt < 2; ++mt)
            af[mt] = *(const bf16x8*)(a_s[cur] + (wm * 32 + mt * 16 + r) * 40 + qd * 8);
#pragma unroll
        for (int nt = 0; nt < 2; ++nt)
            bf[nt] = *(const bf16x8*)(b_s[cur] + (wn * 32 + nt * 16 + r) * 40 + qd * 8);
#pragma unroll
        for (int mt = 0; mt < 2; ++mt)
#pragma unroll
            for (int nt = 0; nt < 2; ++nt)
                acc[mt][nt] = MFMA(af[mt], bf[nt], acc[mt][nt]);

        if (more) write_buf(cur ^ 1);
        BAR_LGKM();
    }

#pragma unroll
    for (int mt = 0; mt < 2; ++mt) {
#pragma unroll
        for (int nt = 0; nt < 2; ++nt) {
#pragma unroll
            for (int j = 0; j < 4; ++j) {
                int o = m0 + wm * 32 + mt * 16 + qd * 4 + j;
                int s = n0 + wn * 32 + nt * 16 + r;
                size_t idx = (size_t)(b * 256 + o) * 4096 + s;
                out[idx] = acc[mt][nt][j] + bo[o] + x[idx];
            }
        }
    }
}

// ---------------------------------------------------------------------------
extern "C" void kernel_launch(void* const* d_in, const int* in_sizes, int n_in,
                              void* d_out, int out_size, void* d_ws, size_t ws_size,
                              hipStream_t stream) {
    const float* x = (const float*)d_in[0];
    const float* gn_w = (const float*)d_in[1];
    const float* gn_b = (const float*)d_in[2];
    const float* wq = (const float*)d_in[3];
    const float* wk = (const float*)d_in[4];
    const float* wv = (const float*)d_in[5];
    const float* wo = (const float*)d_in[6];
    const float* bo = (const float*)d_in[7];
    float* out = (float*)d_out;

    char* ws = (char*)d_ws;
    u16* attnT = (u16*)(ws);                        // [0,4M)
    u16* Q     = (u16*)(ws + (4u << 20));           // [b][h][s][d] (scaled log2e/16)
    u16* Kp    = (u16*)(ws + (8u << 20));           // [b][h][s][d]
    u16* Vp    = (u16*)(ws + (12u << 20));          // [b][h][d][s]
    u16* Wbf   = (u16*)(ws + (16u << 20));          // 512 KB
    float2* part = (float2*)(ws + (16u << 20) + 524288);

    size_t opart_off = (size_t)17 << 20;
    size_t osplit = 8ull * 4096 * 64 * 2;            // 4 MB per split
    int nsplit = (ws_size >= opart_off + 4 * osplit + 4ull * 32768 * 4 + 4096) ? 4 : 2;
    u16* Opart = (u16*)(ws + opart_off);
    float* Lpart = (float*)(ws + opart_off + (size_t)nsplit * osplit);

    prep_kernel<<<512, 256, 0, stream>>>(wq, wk, wv, wo, x, Wbf, part);
    qkv_gemm<<<dim3(128, 6), 256, 0, stream>>>(x, gn_w, gn_b, part, Wbf, Q, Kp, Vp);
    attn_kernel<1><<<dim3(8 * nsplit, 32), 256, 0, stream>>>(
        Q, Kp, Vp, Opart, Lpart, 128 / nsplit);
    attn_combine<<<512, 256, 0, stream>>>(Opart, Lpart, attnT, nsplit);
    out_gemm<<<dim3(256, 2), 256, 0, stream>>>(attnT, Wbf + 3 * 65536, bo, x, out);
}